// Round 16
// baseline (127.983 us; speedup 1.0000x reference)
//
#include <hip/hip_runtime.h>
#include <hip/hip_bf16.h>

typedef __bf16 bf16x8 __attribute__((ext_vector_type(8)));
typedef float  f32x4  __attribute__((ext_vector_type(4)));
typedef float  f32x16 __attribute__((ext_vector_type(16)));

#define NB 16
#define NC 32
#define NH 32
#define NW 2048
#define NK (NC*NH)   // 1024
#define LOG2E 1.4426950408889634f
#define KP 40        // LDS k-pitch for fallback proj

static __device__ __forceinline__ unsigned int pk2(float a, float b) {
    union { __bf16 h[2]; unsigned int u; } z;
    z.h[0] = (__bf16)a; z.h[1] = (__bf16)b;
    return z.u;
}

// ---------------------------------------------------------------------------
// Kernel 0: weights -> bf16. wb layout [3][32][1024]; wq scaled by log2e.
// ---------------------------------------------------------------------------
__global__ __launch_bounds__(256) void wprep_kernel(
    const float* __restrict__ wq, const float* __restrict__ wk,
    const float* __restrict__ wv, __bf16* __restrict__ wb)
{
    const int i = blockIdx.x * 256 + threadIdx.x;        // 24576 float4 units
    const float* srcs[3] = { wq, wk, wv };
    float4 v = *(const float4*)(srcs[i >> 13] + (size_t)(i & 8191) * 4);
    const float sc = (i >> 13) == 0 ? LOG2E : 1.0f;
    union { __bf16 h[4]; unsigned long long u; } z;
    z.h[0] = (__bf16)(v.x * sc); z.h[1] = (__bf16)(v.y * sc);
    z.h[2] = (__bf16)(v.z * sc); z.h[3] = (__bf16)(v.w * sc);
    *(unsigned long long*)(wb + (size_t)i * 4) = z.u;
}

// ---------------------------------------------------------------------------
// Kernel A: x [b][k][w] fp32 -> xT [b][w][k] bf16.  Pure streaming transpose:
// ingest 2k x 4w micro-tiles (two float4s), pk2 k-pairs into dwords, LDS
// [128w][36 kpair-dwords], egress coalesced 16B (8 k-contig bf16) chunks.
// No MFMA, no inter-step barriers: the strided x read in its best form.
// ---------------------------------------------------------------------------
__global__ __launch_bounds__(256) void xtrans_kernel(
    const float* __restrict__ x, __bf16* __restrict__ xT)
{
    const int b  = blockIdx.x >> 8;
    const int kt = (blockIdx.x >> 4) & 15;   // k-tile of 64
    const int wt = blockIdx.x & 15;          // w-tile of 128
    const int k0 = kt * 64, w0 = wt * 128;
    __shared__ unsigned int tile[128][36];   // kpair dwords, padded pitch

    const float* xb = x + ((size_t)b * NK + k0) * NW + w0;
    #pragma unroll
    for (int i = 0; i < 4; ++i) {
        const int flat = i * 256 + threadIdx.x;
        const int kp = flat >> 5;            // 0..31
        const int wq = flat & 31;            // 0..31
        const float4 a = *(const float4*)(xb + (size_t)(2*kp)   * NW + wq*4);
        const float4 c = *(const float4*)(xb + (size_t)(2*kp+1) * NW + wq*4);
        tile[wq*4+0][kp] = pk2(a.x, c.x);
        tile[wq*4+1][kp] = pk2(a.y, c.y);
        tile[wq*4+2][kp] = pk2(a.z, c.z);
        tile[wq*4+3][kp] = pk2(a.w, c.w);
    }
    __syncthreads();
    __bf16* dst = xT + ((size_t)b * NW + w0) * NK + k0;
    #pragma unroll
    for (int i = 0; i < 4; ++i) {
        const int flat = i * 256 + threadIdx.x;
        const int w = flat >> 3, c4 = flat & 7;
        uint4 v;
        v.x = tile[w][c4*4+0]; v.y = tile[w][c4*4+1];
        v.z = tile[w][c4*4+2]; v.w = tile[w][c4*4+3];
        *(uint4*)(dst + (size_t)w * NK + c4*8) = v;
    }
}

// ---------------------------------------------------------------------------
// Kernel 1 (lite): QKV projection from xT — R2/R12 verified structure, but
// A-fragments are single bf16x8 DIRECT global loads (k-contiguous in xT).
// 4-way K-split, 48 KB single-round combine, V written direct [B][32][W].
// Zero per-step LDS staging, zero main-loop barriers.
// ---------------------------------------------------------------------------
__global__ __launch_bounds__(256) void projlite_kernel(
    const __bf16* __restrict__ xT, const __bf16* __restrict__ wb,
    const float* __restrict__ bq, const float* __restrict__ bk,
    const float* __restrict__ bv,
    __bf16* __restrict__ qT, __bf16* __restrict__ kT, __bf16* __restrict__ V)
{
    const int b    = blockIdx.x >> 6;
    const int wt   = blockIdx.x & 63;
    const int wave = threadIdx.x >> 6;       // = K slice
    const int lane = threadIdx.x & 63;
    const int g    = lane >> 4;
    const int lr   = lane & 15;
    const int w0   = wt * 32;

    const __bf16* xTb = xT + (size_t)b * NW * NK;
    const int k0 = wave * 256;

    f32x4 acc[2][6];
    #pragma unroll
    for (int mt = 0; mt < 2; ++mt)
        #pragma unroll
        for (int nt = 0; nt < 6; ++nt)
            acc[mt][nt] = f32x4{0.f, 0.f, 0.f, 0.f};

    #pragma unroll
    for (int ki = 0; ki < 8; ++ki) {
        const int kk = k0 + ki * 32;
        bf16x8 af[2];
        #pragma unroll
        for (int mt = 0; mt < 2; ++mt)
            af[mt] = *(const bf16x8*)(xTb + (size_t)(w0 + mt*16 + lr) * NK + kk + g*8);
        bf16x8 bfv[6];
        #pragma unroll
        for (int nt = 0; nt < 6; ++nt)
            bfv[nt] = *(const bf16x8*)(wb + (size_t)(nt >> 1) * 32768
                                          + (size_t)((nt & 1) * 16 + lr) * NK
                                          + kk + g*8);
        #pragma unroll
        for (int mt = 0; mt < 2; ++mt)
            #pragma unroll
            for (int nt = 0; nt < 6; ++nt)
                acc[mt][nt] = __builtin_amdgcn_mfma_f32_16x16x32_bf16(
                    af[mt], bfv[nt], acc[mt][nt], 0, 0, 0);
    }

    // ---- combine the 4 K-slices through LDS (single round, 48 KB) ----
    __shared__ f32x4 part[4][12][64];
    #pragma unroll
    for (int mt = 0; mt < 2; ++mt)
        #pragma unroll
        for (int nt = 0; nt < 6; ++nt)
            part[wave][mt*6 + nt][lane] = acc[mt][nt];
    __syncthreads();

    const int mt     = wave & 1;
    const int ntbase = (wave >> 1) * 3;
    const float* biases[3] = { bq, bk, bv };
    #pragma unroll
    for (int nti = 0; nti < 3; ++nti) {
        const int nt = ntbase + nti;
        const int fi = mt*6 + nt;
        f32x4 s = part[0][fi][lane];
        #pragma unroll
        for (int sl = 1; sl < 4; ++sl) s += part[sl][fi][lane];
        const int pid = nt >> 1;                 // 0=q,1=k,2=v
        const int o   = (nt & 1) * 16 + lr;
        float bb = biases[pid][o];
        if (pid == 0) bb *= LOG2E;
        if (pid < 2) {
            __bf16* dst = (pid ? kT : qT) + (size_t)b * NW * NC;
            #pragma unroll
            for (int r = 0; r < 4; ++r) {
                const int w = w0 + mt*16 + g*4 + r;
                dst[(size_t)w * NC + o] = (__bf16)(s[r] + bb);
            }
        } else {
            union { __bf16 h[4]; unsigned long long u; } z;
            #pragma unroll
            for (int r = 0; r < 4; ++r) z.h[r] = (__bf16)(s[r] + bb);
            __bf16* dst = V + ((size_t)b * NC + o) * NW + (w0 + mt*16 + g*4);
            *(unsigned long long*)dst = z.u;
        }
    }
}

// ---------------------------------------------------------------------------
// Kernel 1-fallback (R14 v4): used only if ws_size can't hold xT.
// ---------------------------------------------------------------------------
__global__ __launch_bounds__(384) void projfb_kernel(
    const float* __restrict__ x, const __bf16* __restrict__ wb,
    const float* __restrict__ bq, const float* __restrict__ bk,
    const float* __restrict__ bv,
    __bf16* __restrict__ qT, __bf16* __restrict__ kT, __bf16* __restrict__ V)
{
    const int b    = blockIdx.x >> 6;
    const int wt   = blockIdx.x & 63;
    const int nt   = threadIdx.x >> 6;
    const int lane = threadIdx.x & 63;
    const int g    = lane >> 4;
    const int lr   = lane & 15;
    const int w0   = wt * 32;

    __shared__ __bf16 tile[2][32][KP];

    const float* xb = x + (size_t)b * NK * NW;
    const int skr = threadIdx.x >> 3;
    const int swc = (threadIdx.x & 7) * 4;
    const bool stager = (threadIdx.x < 256);
    const float* xs = xb + w0 + swc;

    const __bf16* wrow = wb + (size_t)(nt >> 1) * 32768
                            + (size_t)((nt & 1) * 16 + lr) * NK;

    f32x4 acc0 = {0.f,0.f,0.f,0.f}, acc1 = {0.f,0.f,0.f,0.f};

    f32x4 xv;
    if (stager) {
        xv = *(const f32x4*)(xs + (size_t)skr * NW);
        __bf16* wp = &tile[0][swc][skr];
        wp[0*KP] = (__bf16)xv[0]; wp[1*KP] = (__bf16)xv[1];
        wp[2*KP] = (__bf16)xv[2]; wp[3*KP] = (__bf16)xv[3];
    }
    bf16x8 Bcur = *(const bf16x8*)(wrow + g*8);
    __syncthreads();

    for (int s = 0; s < 32; ++s) {
        const int cur = s & 1;
        f32x4 xn;
        if (s < 31 && stager)
            xn = *(const f32x4*)(xs + (size_t)((s+1)*32 + skr) * NW);
        bf16x8 Bnext;
        if (s < 31)
            Bnext = *(const bf16x8*)(wrow + (s+1)*32 + g*8);

        const bf16x8 af0 = *(const bf16x8*)&tile[cur][lr][g*8];
        const bf16x8 af1 = *(const bf16x8*)&tile[cur][16 + lr][g*8];
        acc0 = __builtin_amdgcn_mfma_f32_16x16x32_bf16(af0, Bcur, acc0, 0, 0, 0);
        acc1 = __builtin_amdgcn_mfma_f32_16x16x32_bf16(af1, Bcur, acc1, 0, 0, 0);

        if (s < 31 && stager) {
            __bf16* wp = &tile[cur ^ 1][swc][skr];
            wp[0*KP] = (__bf16)xn[0]; wp[1*KP] = (__bf16)xn[1];
            wp[2*KP] = (__bf16)xn[2]; wp[3*KP] = (__bf16)xn[3];
        }
        Bcur = Bnext;
        __syncthreads();
    }

    const int pid = nt >> 1;
    const int o   = (nt & 1) * 16 + lr;
    const float* biases[3] = { bq, bk, bv };
    float bb = biases[pid][o];
    if (pid == 0) bb *= LOG2E;

    if (pid < 2) {
        __bf16* dst = (pid ? kT : qT) + (size_t)b * NW * NC;
        #pragma unroll
        for (int r = 0; r < 4; ++r) {
            dst[(size_t)(w0 +      g*4 + r) * NC + o] = (__bf16)(acc0[r] + bb);
            dst[(size_t)(w0 + 16 + g*4 + r) * NC + o] = (__bf16)(acc1[r] + bb);
        }
    } else {
        __bf16* dst = V + ((size_t)b * NC + o) * NW + w0;
        union { __bf16 h[4]; unsigned long long u; } z0, z1;
        #pragma unroll
        for (int r = 0; r < 4; ++r) {
            z0.h[r] = (__bf16)(acc0[r] + bb);
            z1.h[r] = (__bf16)(acc1[r] + bb);
        }
        *(unsigned long long*)(dst +      g*4) = z0.u;
        *(unsigned long long*)(dst + 16 + g*4) = z1.u;
    }
}

// ---------------------------------------------------------------------------
// Kernel 2: flash attention (R10, unchanged/verified): fixed-max softmax,
// sigma-permuted K rows (lane-local PV fragments), software-pipelined loop,
// exp2 via __builtin_amdgcn_exp2f, NT out stores.
// ---------------------------------------------------------------------------
__global__ __launch_bounds__(256) void attn_kernel(
    const float* __restrict__ x,
    const __bf16* __restrict__ qT, const __bf16* __restrict__ kT,
    const __bf16* __restrict__ V,
    float* __restrict__ out)
{
    const int b    = blockIdx.x >> 6;
    const int wt   = blockIdx.x & 63;
    const int w0   = wt * 32;
    const int wave = threadIdx.x >> 6;        // KV slice 0..3
    const int lane = threadIdx.x & 63;
    const int wl = lane & 31, hi = lane >> 5;
    const int swl = (wl & 0x13) | ((wl & 4) << 1) | ((wl & 8) >> 1);

    const __bf16* qTb = qT + (size_t)b * NW * NC;
    const __bf16* kTb = kT + (size_t)b * NW * NC;
    const __bf16* Vb  = V  + (size_t)b * NC * NW;

    const __bf16* qrow = qTb + (size_t)(w0 + wl) * NC;
    const bf16x8 qf0 = *(const bf16x8*)(qrow + hi*8);
    const bf16x8 qf1 = *(const bf16x8*)(qrow + 16 + hi*8);

    f32x16 acc, z16;
    #pragma unroll
    for (int r = 0; r < 16; ++r) { acc[r] = 0.f; z16[r] = 0.f; }
    float lsum = 0.f;

    const int vbeg = wave * 512;
    const __bf16* kbase = kTb + (size_t)swl * NC;
    const __bf16* vbase = Vb + (size_t)wl * NW;

#define KLD0(V0) (*(const bf16x8*)(kbase + (size_t)(V0) * NC + hi*8))
#define KLD1(V0) (*(const bf16x8*)(kbase + (size_t)(V0) * NC + 16 + hi*8))
#define VLD0(V0) (*(const bf16x8*)(vbase + (V0) + hi*8))
#define VLD1(V0) (*(const bf16x8*)(vbase + (V0) + 16 + hi*8))

    bf16x8 k0r = KLD0(vbeg), k1r = KLD1(vbeg);
    f32x16 s_cur = __builtin_amdgcn_mfma_f32_32x32x16_bf16(k0r, qf0, z16, 0, 0, 0);
    s_cur = __builtin_amdgcn_mfma_f32_32x32x16_bf16(k1r, qf1, s_cur, 0, 0, 0);
    k0r = KLD0(vbeg + 32); k1r = KLD1(vbeg + 32);
    bf16x8 v0r = VLD0(vbeg), v1r = VLD1(vbeg);

    #pragma unroll
    for (int it = 0; it < 16; ++it) {
        f32x16 s_next;
        if (it < 15) {
            s_next = __builtin_amdgcn_mfma_f32_32x32x16_bf16(k0r, qf0, z16, 0, 0, 0);
            s_next = __builtin_amdgcn_mfma_f32_32x32x16_bf16(k1r, qf1, s_next, 0, 0, 0);
        }
        if (it < 14) {
            const int vn = vbeg + (it + 2) * 32;
            k0r = KLD0(vn); k1r = KLD1(vn);
        }

        float p[16];
        #pragma unroll
        for (int r = 0; r < 16; ++r) p[r] = __builtin_amdgcn_exp2f(s_cur[r]);
        float ts[8];
        #pragma unroll
        for (int r = 0; r < 8; ++r) ts[r] = p[r] + p[r+8];
        #pragma unroll
        for (int r = 0; r < 4; ++r) ts[r] += ts[r+4];
        lsum += (ts[0] + ts[1]) + (ts[2] + ts[3]);

        union { unsigned int u[4]; bf16x8 v; } pfa, pfb;
        #pragma unroll
        for (int i = 0; i < 4; ++i) pfa.u[i] = pk2(p[2*i],     p[2*i + 1]);
        #pragma unroll
        for (int i = 0; i < 4; ++i) pfb.u[i] = pk2(p[8 + 2*i], p[8 + 2*i + 1]);

        acc = __builtin_amdgcn_mfma_f32_32x32x16_bf16(v0r, pfa.v, acc, 0, 0, 0);
        acc = __builtin_amdgcn_mfma_f32_32x32x16_bf16(v1r, pfb.v, acc, 0, 0, 0);

        if (it < 15) {
            const int vn = vbeg + (it + 1) * 32;
            v0r = VLD0(vn); v1r = VLD1(vn);
            s_cur = s_next;
        }
    }
#undef KLD0
#undef KLD1
#undef VLD0
#undef VLD1
    lsum += __shfl_xor(lsum, 32);

    __shared__ float sl[4][32];
    __shared__ float sO[4][32][33];
    __shared__ float Of[32][33];

    if (hi == 0) sl[wave][wl] = lsum;
    #pragma unroll
    for (int r = 0; r < 16; ++r) {
        const int c = (r & 3) + 8*(r >> 2) + 4*hi;
        sO[wave][c][wl] = acc[r];
    }
    __syncthreads();

    {
        const int w  = threadIdx.x & 31;
        const int cg = threadIdx.x >> 5;
        const float L = (sl[0][w] + sl[1][w]) + (sl[2][w] + sl[3][w]);
        const float rL = 1.0f / L;
        #pragma unroll
        for (int cc = 0; cc < 4; ++cc) {
            const int c = cg * 4 + cc;
            const float o = ((sO[0][c][w] + sO[1][c][w]) +
                             (sO[2][c][w] + sO[3][c][w]));
            Of[c][w] = o * rL;
        }
    }
    __syncthreads();

    const float* xb = x   + (size_t)b * NC * NH * NW + w0;
    float*       ob = out + (size_t)b * NC * NH * NW + w0;
    const int chunk = threadIdx.x & 7;
    #pragma unroll
    for (int it = 0; it < 32; ++it) {
        const int row = it*32 + (threadIdx.x >> 3);
        const int c = row >> 5, h = row & 31;
        const size_t off = ((size_t)c * NH + h) * NW + chunk*4;
        const f32x4 xv = *(const f32x4*)(xb + off);
        f32x4 ov;
        ov[0] = Of[c][chunk*4 + 0] + xv[0];
        ov[1] = Of[c][chunk*4 + 1] + xv[1];
        ov[2] = Of[c][chunk*4 + 2] + xv[2];
        ov[3] = Of[c][chunk*4 + 3] + xv[3];
        __builtin_nontemporal_store(ov, (f32x4*)(ob + off));
    }
}

extern "C" void kernel_launch(void* const* d_in, const int* in_sizes, int n_in,
                              void* d_out, int out_size, void* d_ws, size_t ws_size,
                              hipStream_t stream)
{
    const float* x  = (const float*)d_in[0];
    const float* wq = (const float*)d_in[1];
    const float* bq = (const float*)d_in[2];
    const float* wk = (const float*)d_in[3];
    const float* bk = (const float*)d_in[4];
    const float* wv = (const float*)d_in[5];
    const float* bv = (const float*)d_in[6];
    float* out = (float*)d_out;

    // ws layout (bf16): qT@0 (2MB), kT@2MB, V@4MB, wb@6MB, xT@8MB (64MB)
    char* ws = (char*)d_ws;
    __bf16* qT = (__bf16*)(ws);
    __bf16* kT = (__bf16*)(ws + (2u << 20));
    __bf16* V  = (__bf16*)(ws + (4u << 20));
    __bf16* wb = (__bf16*)(ws + (6u << 20));
    __bf16* xT = (__bf16*)(ws + (8u << 20));

    hipLaunchKernelGGL(wprep_kernel, dim3(96), dim3(256), 0, stream, wq, wk, wv, wb);
    if (ws_size >= (size_t)(72u << 20)) {
        hipLaunchKernelGGL(xtrans_kernel, dim3(NB * 256), dim3(256), 0, stream, x, xT);
        hipLaunchKernelGGL(projlite_kernel, dim3(NB * 64), dim3(256), 0, stream,
                           xT, wb, bq, bk, bv, qT, kT, V);
    } else {
        hipLaunchKernelGGL(projfb_kernel, dim3(NB * 64), dim3(384), 0, stream,
                           x, wb, bq, bk, bv, qT, kT, V);
    }
    hipLaunchKernelGGL(attn_kernel, dim3(NB * 64), dim3(256), 0, stream,
                       x, qT, kT, V, out);
}

// Round 17
// 97.411 us; speedup vs baseline: 1.3138x; 1.3138x over previous
//
#include <hip/hip_runtime.h>
#include <hip/hip_bf16.h>

typedef __bf16 bf16x8 __attribute__((ext_vector_type(8)));
typedef float  f32x4  __attribute__((ext_vector_type(4)));
typedef float  f32x16 __attribute__((ext_vector_type(16)));

#define NB 16
#define NC 32
#define NH 32
#define NW 2048
#define NK (NC*NH)   // 1024
#define LOG2E 1.4426950408889634f
#define KP 40        // LDS k-pitch (bf16): 80 B rows

static __device__ __forceinline__ unsigned int pk2(float a, float b) {
    union { __bf16 h[2]; unsigned int u; } z;
    z.h[0] = (__bf16)a; z.h[1] = (__bf16)b;
    return z.u;
}

// ---------------------------------------------------------------------------
// Kernel 0: weights -> bf16. wb layout [3][32][1024]; wq scaled by log2e.
// ---------------------------------------------------------------------------
__global__ __launch_bounds__(256) void wprep_kernel(
    const float* __restrict__ wq, const float* __restrict__ wk,
    const float* __restrict__ wv, __bf16* __restrict__ wb)
{
    const int i = blockIdx.x * 256 + threadIdx.x;        // 24576 float4 units
    const float* srcs[3] = { wq, wk, wv };
    float4 v = *(const float4*)(srcs[i >> 13] + (size_t)(i & 8191) * 4);
    const float sc = (i >> 13) == 0 ? LOG2E : 1.0f;
    union { __bf16 h[4]; unsigned long long u; } z;
    z.h[0] = (__bf16)(v.x * sc); z.h[1] = (__bf16)(v.y * sc);
    z.h[2] = (__bf16)(v.z * sc); z.h[3] = (__bf16)(v.w * sc);
    *(unsigned long long*)(wb + (size_t)i * 4) = z.u;
}

// ---------------------------------------------------------------------------
// Kernel 1 (v6): QKV projection, BM=128, producer/consumer waves.
// Block = 512 thr: waves 0..5 = compute (wave nt -> 16 output channels x
// 128 w, 8 mtiles), waves 6..7 = stagers. Per 32k-step stagers read 512B
// CONTIGUOUS per x-row (8 float4/thread, 4 thr/row) -- 4x wider per-row
// requests than every previous proj -- and ds_write the transposed
// [128w][40k] bf16 tile (20.5 KB double-buffered, one barrier/step).
// Compute waves: 8 ds_read_b128 + 8 MFMA per step, B-frags reg-prefetched.
// Grid = 256 blocks (1/CU).
// ---------------------------------------------------------------------------
__global__ __launch_bounds__(512) void proj_kernel(
    const float* __restrict__ x, const __bf16* __restrict__ wb,
    const float* __restrict__ bq, const float* __restrict__ bk,
    const float* __restrict__ bv,
    __bf16* __restrict__ qT, __bf16* __restrict__ kT, __bf16* __restrict__ V)
{
    const int b    = blockIdx.x >> 4;
    const int wt   = blockIdx.x & 15;
    const int nt   = threadIdx.x >> 6;       // 0..5 compute, 6..7 stagers
    const int lane = threadIdx.x & 63;
    const int g    = lane >> 4;
    const int lr   = lane & 15;
    const int w0   = wt * 128;

    __shared__ __bf16 tile[2][128][KP];      // 20.5 KB

    const float* xb = x + (size_t)b * NK * NW;
    const bool stager = (threadIdx.x >= 384);

    // stager mapping: ts 0..127 -> row = ts>>2 (0..31), 512B quadrant = ts&3
    const int ts   = threadIdx.x - 384;
    const int srow = ts >> 2;
    const int sq   = ts & 3;
    const float* xs = xb + w0 + sq * 32;     // +32 floats per quadrant

    f32x4 xr[8];                             // stager regs: 8 float4 = 512B

#define SLOAD(S)                                                              \
    _Pragma("unroll")                                                         \
    for (int j = 0; j < 8; ++j)                                               \
        xr[j] = *(const f32x4*)(xs + (size_t)((S)*32 + srow) * NW + j*4);

#define SWRITE(BUF)                                                           \
    _Pragma("unroll")                                                         \
    for (int j = 0; j < 8; ++j) {                                             \
        const int wbase = sq*32 + j*4;                                        \
        _Pragma("unroll")                                                     \
        for (int e = 0; e < 4; ++e)                                           \
            tile[BUF][wbase + e][srow] = (__bf16)xr[j][e];                    \
    }

    // compute-wave state
    const __bf16* wrow = wb + (size_t)(nt >> 1) * 32768
                            + (size_t)((nt & 1) * 16 + lr) * NK;
    f32x4 acc[8];
    #pragma unroll
    for (int m = 0; m < 8; ++m) acc[m] = f32x4{0.f,0.f,0.f,0.f};

    // ---- prologue ----
    if (stager) {
        SLOAD(0);
        SWRITE(0);
        SLOAD(1);
    }
    bf16x8 Bcur;
    if (!stager) Bcur = *(const bf16x8*)(wrow + g*8);
    __syncthreads();

    #pragma unroll
    for (int s = 0; s < 32; ++s) {
        if (stager) {
            if (s < 31) { SWRITE((s + 1) & 1); }     // x(s+1) -> other buf
            if (s < 30) { SLOAD(s + 2); }            // issue x(s+2)
        } else {
            bf16x8 Bnext;
            if (s < 31) Bnext = *(const bf16x8*)(wrow + (s+1)*32 + g*8);
            #pragma unroll
            for (int m = 0; m < 8; ++m) {
                const bf16x8 af = *(const bf16x8*)&tile[s & 1][m*16 + lr][g*8];
                acc[m] = __builtin_amdgcn_mfma_f32_16x16x32_bf16(
                    af, Bcur, acc[m], 0, 0, 0);
            }
            Bcur = Bnext;
        }
        __syncthreads();
    }
#undef SLOAD
#undef SWRITE

    // ---- epilogue (compute waves only) ----
    if (!stager) {
        const int pid = nt >> 1;             // 0=q,1=k,2=v
        const int o   = (nt & 1) * 16 + lr;
        const float* biases[3] = { bq, bk, bv };
        float bb = biases[pid][o];
        if (pid == 0) bb *= LOG2E;

        if (pid < 2) {
            __bf16* dst = (pid ? kT : qT) + (size_t)b * NW * NC;
            #pragma unroll
            for (int m = 0; m < 8; ++m)
                #pragma unroll
                for (int r = 0; r < 4; ++r) {
                    const int w = w0 + m*16 + g*4 + r;
                    dst[(size_t)w * NC + o] = (__bf16)(acc[m][r] + bb);
                }
        } else {
            __bf16* dst = V + ((size_t)b * NC + o) * NW + w0;
            #pragma unroll
            for (int m = 0; m < 8; ++m) {
                union { __bf16 h[4]; unsigned long long u; } z;
                #pragma unroll
                for (int r = 0; r < 4; ++r) z.h[r] = (__bf16)(acc[m][r] + bb);
                *(unsigned long long*)(dst + m*16 + g*4) = z.u;
            }
        }
    }
}

// ---------------------------------------------------------------------------
// Kernel 2: flash attention (R10, unchanged/verified): fixed-max softmax,
// sigma-permuted K rows (lane-local PV fragments), software-pipelined loop,
// exp2 via __builtin_amdgcn_exp2f, NT out stores.
// ---------------------------------------------------------------------------
__global__ __launch_bounds__(256) void attn_kernel(
    const float* __restrict__ x,
    const __bf16* __restrict__ qT, const __bf16* __restrict__ kT,
    const __bf16* __restrict__ V,
    float* __restrict__ out)
{
    const int b    = blockIdx.x >> 6;
    const int wt   = blockIdx.x & 63;
    const int w0   = wt * 32;
    const int wave = threadIdx.x >> 6;        // KV slice 0..3
    const int lane = threadIdx.x & 63;
    const int wl = lane & 31, hi = lane >> 5;
    const int swl = (wl & 0x13) | ((wl & 4) << 1) | ((wl & 8) >> 1);

    const __bf16* qTb = qT + (size_t)b * NW * NC;
    const __bf16* kTb = kT + (size_t)b * NW * NC;
    const __bf16* Vb  = V  + (size_t)b * NC * NW;

    const __bf16* qrow = qTb + (size_t)(w0 + wl) * NC;
    const bf16x8 qf0 = *(const bf16x8*)(qrow + hi*8);
    const bf16x8 qf1 = *(const bf16x8*)(qrow + 16 + hi*8);

    f32x16 acc, z16;
    #pragma unroll
    for (int r = 0; r < 16; ++r) { acc[r] = 0.f; z16[r] = 0.f; }
    float lsum = 0.f;

    const int vbeg = wave * 512;
    const __bf16* kbase = kTb + (size_t)swl * NC;
    const __bf16* vbase = Vb + (size_t)wl * NW;

#define KLD0(V0) (*(const bf16x8*)(kbase + (size_t)(V0) * NC + hi*8))
#define KLD1(V0) (*(const bf16x8*)(kbase + (size_t)(V0) * NC + 16 + hi*8))
#define VLD0(V0) (*(const bf16x8*)(vbase + (V0) + hi*8))
#define VLD1(V0) (*(const bf16x8*)(vbase + (V0) + 16 + hi*8))

    bf16x8 k0r = KLD0(vbeg), k1r = KLD1(vbeg);
    f32x16 s_cur = __builtin_amdgcn_mfma_f32_32x32x16_bf16(k0r, qf0, z16, 0, 0, 0);
    s_cur = __builtin_amdgcn_mfma_f32_32x32x16_bf16(k1r, qf1, s_cur, 0, 0, 0);
    k0r = KLD0(vbeg + 32); k1r = KLD1(vbeg + 32);
    bf16x8 v0r = VLD0(vbeg), v1r = VLD1(vbeg);

    #pragma unroll
    for (int it = 0; it < 16; ++it) {
        f32x16 s_next;
        if (it < 15) {
            s_next = __builtin_amdgcn_mfma_f32_32x32x16_bf16(k0r, qf0, z16, 0, 0, 0);
            s_next = __builtin_amdgcn_mfma_f32_32x32x16_bf16(k1r, qf1, s_next, 0, 0, 0);
        }
        if (it < 14) {
            const int vn = vbeg + (it + 2) * 32;
            k0r = KLD0(vn); k1r = KLD1(vn);
        }

        float p[16];
        #pragma unroll
        for (int r = 0; r < 16; ++r) p[r] = __builtin_amdgcn_exp2f(s_cur[r]);
        float ts[8];
        #pragma unroll
        for (int r = 0; r < 8; ++r) ts[r] = p[r] + p[r+8];
        #pragma unroll
        for (int r = 0; r < 4; ++r) ts[r] += ts[r+4];
        lsum += (ts[0] + ts[1]) + (ts[2] + ts[3]);

        union { unsigned int u[4]; bf16x8 v; } pfa, pfb;
        #pragma unroll
        for (int i = 0; i < 4; ++i) pfa.u[i] = pk2(p[2*i],     p[2*i + 1]);
        #pragma unroll
        for (int i = 0; i < 4; ++i) pfb.u[i] = pk2(p[8 + 2*i], p[8 + 2*i + 1]);

        acc = __builtin_amdgcn_mfma_f32_32x32x16_bf16(v0r, pfa.v, acc, 0, 0, 0);
        acc = __builtin_amdgcn_mfma_f32_32x32x16_bf16(v1r, pfb.v, acc, 0, 0, 0);

        if (it < 15) {
            const int vn = vbeg + (it + 1) * 32;
            v0r = VLD0(vn); v1r = VLD1(vn);
            s_cur = s_next;
        }
    }
#undef KLD0
#undef KLD1
#undef VLD0
#undef VLD1
    lsum += __shfl_xor(lsum, 32);

    __shared__ float sl[4][32];
    __shared__ float sO[4][32][33];
    __shared__ float Of[32][33];

    if (hi == 0) sl[wave][wl] = lsum;
    #pragma unroll
    for (int r = 0; r < 16; ++r) {
        const int c = (r & 3) + 8*(r >> 2) + 4*hi;
        sO[wave][c][wl] = acc[r];
    }
    __syncthreads();

    {
        const int w  = threadIdx.x & 31;
        const int cg = threadIdx.x >> 5;
        const float L = (sl[0][w] + sl[1][w]) + (sl[2][w] + sl[3][w]);
        const float rL = 1.0f / L;
        #pragma unroll
        for (int cc = 0; cc < 2; ++cc) {
            const int c = cg * 2 + cc + ((cg >= 8) ? 0 : 0);
            // (cg 0..7 covers c 0..15; use two rounds below instead)
        }
        #pragma unroll
        for (int cc = 0; cc < 4; ++cc) {
            const int c = cg * 4 + cc;
            const float o = ((sO[0][c][w] + sO[1][c][w]) +
                             (sO[2][c][w] + sO[3][c][w]));
            Of[c][w] = o * rL;
        }
    }
    __syncthreads();

    const float* xb = x   + (size_t)b * NC * NH * NW + w0;
    float*       ob = out + (size_t)b * NC * NH * NW + w0;
    const int chunk = threadIdx.x & 7;
    #pragma unroll
    for (int it = 0; it < 32; ++it) {
        const int row = it*32 + (threadIdx.x >> 3);
        const int c = row >> 5, h = row & 31;
        const size_t off = ((size_t)c * NH + h) * NW + chunk*4;
        const f32x4 xv = *(const f32x4*)(xb + off);
        f32x4 ov;
        ov[0] = Of[c][chunk*4 + 0] + xv[0];
        ov[1] = Of[c][chunk*4 + 1] + xv[1];
        ov[2] = Of[c][chunk*4 + 2] + xv[2];
        ov[3] = Of[c][chunk*4 + 3] + xv[3];
        __builtin_nontemporal_store(ov, (f32x4*)(ob + off));
    }
}

extern "C" void kernel_launch(void* const* d_in, const int* in_sizes, int n_in,
                              void* d_out, int out_size, void* d_ws, size_t ws_size,
                              hipStream_t stream)
{
    const float* x  = (const float*)d_in[0];
    const float* wq = (const float*)d_in[1];
    const float* bq = (const float*)d_in[2];
    const float* wk = (const float*)d_in[3];
    const float* bk = (const float*)d_in[4];
    const float* wv = (const float*)d_in[5];
    const float* bv = (const float*)d_in[6];
    float* out = (float*)d_out;

    // ws layout (bf16): qT [B][W][32] @0, kT @2MB, V [B][32][W] @4MB, wb @6MB
    char* ws = (char*)d_ws;
    __bf16* qT = (__bf16*)(ws);
    __bf16* kT = (__bf16*)(ws + (2u << 20));
    __bf16* V  = (__bf16*)(ws + (4u << 20));
    __bf16* wb = (__bf16*)(ws + (6u << 20));

    hipLaunchKernelGGL(wprep_kernel, dim3(96), dim3(256), 0, stream, wq, wk, wv, wb);
    hipLaunchKernelGGL(proj_kernel, dim3(NB * 16), dim3(512), 0, stream,
                       x, wb, bq, bk, bv, qT, kT, V);
    hipLaunchKernelGGL(attn_kernel, dim3(NB * 64), dim3(256), 0, stream,
                       x, qT, kT, V, out);
}